// Round 1
// baseline (7726.543 us; speedup 1.0000x reference)
//
#include <hip/hip_runtime.h>
#include <math.h>

#define NB 16384   // batch
#define SROWS 32   // rows per SDE workgroup

__device__ __forceinline__ float swishf(float x) {
    // x * sigmoid(x) = x / (1 + e^-x)
    return __fdividef(x, 1.0f + __expf(-x));
}

__device__ __forceinline__ float softplusf(float x) {
    // log1p(exp(x)), overflow-safe
    return fmaxf(x, 0.0f) + log1pf(__expf(-fabsf(x)));
}

// ---------------------------------------------------------------------------
// Encoder GEMM: C[M,N] = act(A[M,K] @ W[K,N] + bias[N] (+ res[M,N]))
// 64x64 tile, BK=16, 256 threads, 4x4 microtile. K multiple of 16, N mult 64.
// ---------------------------------------------------------------------------
__global__ __launch_bounds__(256)
void gemm_bias_act(const float* __restrict__ A, const float* __restrict__ W,
                   const float* __restrict__ bias, const float* __restrict__ res,
                   float* __restrict__ C, int M, int N, int K, int act)
{
    __shared__ float As[16][68];   // [k][m], padded
    __shared__ float Bs[16][68];   // [k][n], padded

    const int tid  = threadIdx.x;
    const int row0 = blockIdx.y * 64;
    const int col0 = blockIdx.x * 64;
    const int tx = tid & 15;
    const int ty = tid >> 4;

    const int lm = tid >> 2;          // 0..63 : A row within tile
    const int lk = (tid & 3) << 2;    // 0,4,8,12 : A k quad
    const int bk = tid >> 4;          // 0..15 : W k row
    const int bn = (tid & 15) << 2;   // 0..60 : W col quad

    float acc[4][4] = {};

    for (int k0 = 0; k0 < K; k0 += 16) {
        const float4 av = *(const float4*)&A[(size_t)(row0 + lm) * K + k0 + lk];
        const float4 bv = *(const float4*)&W[(size_t)(k0 + bk) * N + col0 + bn];
        As[lk + 0][lm] = av.x;
        As[lk + 1][lm] = av.y;
        As[lk + 2][lm] = av.z;
        As[lk + 3][lm] = av.w;
        *(float4*)&Bs[bk][bn] = bv;
        __syncthreads();
        #pragma unroll
        for (int k = 0; k < 16; ++k) {
            const float4 a = *(const float4*)&As[k][ty << 2];
            const float4 b = *(const float4*)&Bs[k][tx << 2];
            acc[0][0] += a.x*b.x; acc[0][1] += a.x*b.y; acc[0][2] += a.x*b.z; acc[0][3] += a.x*b.w;
            acc[1][0] += a.y*b.x; acc[1][1] += a.y*b.y; acc[1][2] += a.y*b.z; acc[1][3] += a.y*b.w;
            acc[2][0] += a.z*b.x; acc[2][1] += a.z*b.y; acc[2][2] += a.z*b.z; acc[2][3] += a.z*b.w;
            acc[3][0] += a.w*b.x; acc[3][1] += a.w*b.y; acc[3][2] += a.w*b.z; acc[3][3] += a.w*b.w;
        }
        __syncthreads();
    }

    #pragma unroll
    for (int i = 0; i < 4; ++i) {
        const int r = row0 + (ty << 2) + i;
        #pragma unroll
        for (int j = 0; j < 4; ++j) {
            const int c = col0 + (tx << 2) + j;
            float v = acc[i][j] + bias[c];
            if (res) v += res[(size_t)r * N + c];
            if (act) v = swishf(v);
            C[(size_t)r * N + c] = v;
        }
    }
}

// ---------------------------------------------------------------------------
// mu / s split: lp[NB,128] -> mu = lp[:, :64], s = exp(0.5*lp[:, 64:])
// ---------------------------------------------------------------------------
__global__ __launch_bounds__(256)
void mu_s_kernel(const float* __restrict__ lp, float* __restrict__ mu,
                 float* __restrict__ s)
{
    const int idx = blockIdx.x * 256 + threadIdx.x;   // < NB*64
    const int row = idx >> 6;
    const int c   = idx & 63;
    mu[idx] = lp[(row << 7) + c];
    s[idx]  = expf(0.5f * lp[(row << 7) + 64 + c]);
}

// ---------------------------------------------------------------------------
// SDE phase helpers (per-thread-column, weights in VGPRs, LDS broadcast reads)
// ---------------------------------------------------------------------------

// out[r][j] = swish(t*W[0][j] + sum_k z[r][k]*W[1+k][j] + b[j]), K=65
template<int R>
__device__ __forceinline__ void phase_k65(const float (*zb)[64], float (*out)[256],
                                          const float* __restrict__ W,
                                          const float* __restrict__ b,
                                          float t, int j)
{
    const float w0 = W[j];
    float w[64];
    #pragma unroll
    for (int k = 0; k < 64; ++k) w[k] = W[(k + 1) * 256 + j];
    const float bj = b[j] + t * w0;
    for (int r = 0; r < R; ++r) {
        float p0 = 0.f, p1 = 0.f, p2 = 0.f, p3 = 0.f;
        #pragma unroll
        for (int q = 0; q < 16; ++q) {
            const float4 zv = *(const float4*)&zb[r][q << 2];
            p0 += zv.x * w[(q << 2) + 0];
            p1 += zv.y * w[(q << 2) + 1];
            p2 += zv.z * w[(q << 2) + 2];
            p3 += zv.w * w[(q << 2) + 3];
        }
        out[r][j] = swishf(bj + ((p0 + p1) + (p2 + p3)));
    }
}

// acc[i] += sum_k src[rg*8+i][k] * W[k*64 + c], K=256 (N=64 output phases)
template<int R>
__device__ __forceinline__ void accum_n64(const float (*src)[256],
                                          const float* __restrict__ W,
                                          float* acc, int c, int rg)
{
    for (int ch = 0; ch < 4; ++ch) {
        float w[64];
        #pragma unroll
        for (int k = 0; k < 64; ++k) w[k] = W[((ch << 6) + k) * 64 + c];
        #pragma unroll
        for (int i = 0; i < 8; ++i) {
            const int r = (rg << 3) + i;
            float p0 = 0.f, p1 = 0.f, p2 = 0.f, p3 = 0.f;
            #pragma unroll
            for (int q = 0; q < 16; ++q) {
                const float4 hv = *(const float4*)&src[r][(ch << 6) + (q << 2)];
                p0 += hv.x * w[(q << 2) + 0];
                p1 += hv.y * w[(q << 2) + 1];
                p2 += hv.z * w[(q << 2) + 2];
                p3 += hv.w * w[(q << 2) + 3];
            }
            acc[i] += ((p0 + p1) + (p2 + p3));
        }
    }
}

// ---------------------------------------------------------------------------
// Persistent SDE kernel: all 63 steps in one launch, z kept in LDS.
// 512 WGs x 256 threads, 32 rows each; LDS 72 KB -> 2 WGs/CU.
// ---------------------------------------------------------------------------
__global__ __launch_bounds__(256, 2)
void sde_kernel(const float* __restrict__ ts, const float* __restrict__ noise,
                const float* __restrict__ Wd1, const float* __restrict__ bd1,
                const float* __restrict__ Wd2, const float* __restrict__ bd2,
                const float* __restrict__ Wd3, const float* __restrict__ bd3,
                const float* __restrict__ Wg1, const float* __restrict__ bg1,
                const float* __restrict__ Wg2, const float* __restrict__ bg2,
                float* __restrict__ zpath)
{
    __shared__ float zbuf[SROWS][64];    //  8 KB : persistent z state
    __shared__ float bufA[SROWS][256];   // 32 KB : h1, then g1
    __shared__ float bufB[SROWS][256];   // 32 KB : h2

    const int tid  = threadIdx.x;
    const int row0 = blockIdx.x * SROWS;

    // load z0 from z_path[0]
    #pragma unroll
    for (int i = 0; i < (SROWS * 64 / 4) / 256; ++i) {
        const int f = tid + i * 256;      // float4 index
        const int e = f << 2;             // float index
        const float4 v = *(const float4*)&zpath[(size_t)row0 * 64 + e];
        *(float4*)&zbuf[e >> 6][e & 63] = v;
    }
    __syncthreads();

    for (int step = 0; step < 63; ++step) {
        const float t  = ts[step];
        const float dt = ts[step + 1] - t;
        const float sq = sqrtf(dt);
        const int j = tid;

        // H1 = swish([t,z] @ Wd1 + bd1) -> bufA
        phase_k65<SROWS>(zbuf, bufA, Wd1, bd1, t, j);
        __syncthreads();

        // H2 = swish(H1 @ Wd2 + bd2) -> bufB  (K=256 in 4 chunks, LDS RMW acc)
        {
            const float bj = bd2[j];
            for (int ch = 0; ch < 4; ++ch) {
                float w[64];
                #pragma unroll
                for (int k = 0; k < 64; ++k) w[k] = Wd2[((ch << 6) + k) * 256 + j];
                for (int r = 0; r < SROWS; ++r) {
                    float p0 = 0.f, p1 = 0.f, p2 = 0.f, p3 = 0.f;
                    #pragma unroll
                    for (int q = 0; q < 16; ++q) {
                        const float4 hv = *(const float4*)&bufA[r][(ch << 6) + (q << 2)];
                        p0 += hv.x * w[(q << 2) + 0];
                        p1 += hv.y * w[(q << 2) + 1];
                        p2 += hv.z * w[(q << 2) + 2];
                        p3 += hv.w * w[(q << 2) + 3];
                    }
                    float acc = ((p0 + p1) + (p2 + p3)) + ((ch == 0) ? bj : bufB[r][j]);
                    bufB[r][j] = (ch == 3) ? swishf(acc) : acc;
                }
            }
        }
        __syncthreads();   // bufA consumed; bufB ready

        // G1 = swish([t,z] @ Wg1 + bg1) -> bufA (overwrites h1)
        phase_k65<SROWS>(zbuf, bufA, Wg1, bg1, t, j);
        __syncthreads();   // bufA(g1) ready

        // D = H2 @ Wd3 + bd3 ; G = softplus(G1 @ Wg2 + bg2) ; z update
        {
            const int c  = tid & 63;
            const int rg = tid >> 6;     // 4 row-groups x 8 rows
            float accd[8], accg[8];
            #pragma unroll
            for (int i = 0; i < 8; ++i) { accd[i] = bd3[c]; accg[i] = bg2[c]; }
            accum_n64<SROWS>(bufB, Wd3, accd, c, rg);
            accum_n64<SROWS>(bufA, Wg2, accg, c, rg);

            const size_t nbase = ((size_t)step * NB + row0) * 64;
            float* zo = zpath + ((size_t)(step + 1) * NB + row0) * 64;
            #pragma unroll
            for (int i = 0; i < 8; ++i) {
                const int r = (rg << 3) + i;
                const float g  = softplusf(accg[i]);
                const float zn = zbuf[r][c] + accd[i] * dt
                               + g * sq * noise[nbase + (size_t)r * 64 + c];
                zbuf[r][c] = zn;
                zo[(size_t)r * 64 + c] = zn;
            }
        }
        __syncthreads();   // zbuf ready for next step
    }
}

// ---------------------------------------------------------------------------
extern "C" void kernel_launch(void* const* d_in, const int* in_sizes, int n_in,
                              void* d_out, int out_size, void* d_ws, size_t ws_size,
                              hipStream_t stream)
{
    const float* x      = (const float*)d_in[0];
    const float* ts     = (const float*)d_in[1];
    const float* noise  = (const float*)d_in[2];
    const float* W_in   = (const float*)d_in[3];
    const float* b_in   = (const float*)d_in[4];
    const float* Wb1    = (const float*)d_in[5];
    const float* bb1    = (const float*)d_in[6];
    const float* Wb2    = (const float*)d_in[7];
    const float* bb2    = (const float*)d_in[8];
    const float* W_fo   = (const float*)d_in[9];
    const float* b_fo   = (const float*)d_in[10];
    const float* W_lat  = (const float*)d_in[11];
    const float* b_lat  = (const float*)d_in[12];
    const float* W_init = (const float*)d_in[13];
    const float* b_init = (const float*)d_in[14];
    const float* Wd1    = (const float*)d_in[15];
    const float* bd1    = (const float*)d_in[16];
    const float* Wd2    = (const float*)d_in[17];
    const float* bd2    = (const float*)d_in[18];
    const float* Wd3    = (const float*)d_in[19];
    const float* bd3    = (const float*)d_in[20];
    const float* Wg1    = (const float*)d_in[21];
    const float* bg1    = (const float*)d_in[22];
    const float* Wg2    = (const float*)d_in[23];
    const float* bg2    = (const float*)d_in[24];

    float* out   = (float*)d_out;
    float* mu_o  = out;                              // [NB,64]
    float* s_o   = out + (size_t)NB * 64;            // [NB,64]
    float* zpath = out + (size_t)2 * NB * 64;        // [64,NB,64]

    float* bufH = (float*)d_ws;                      // [NB,256]
    float* bufT = bufH + (size_t)NB * 256;           // [NB,256]
    // total ws use: 32 MB

    const dim3 blk(256);
    auto g = [&](const float* A, const float* W, const float* b,
                 const float* res, float* C, int N, int act) {
        dim3 grd(N / 64, NB / 64);
        gemm_bias_act<<<grd, blk, 0, stream>>>(A, W, b, res, C, NB, N, 256, act);
    };

    // encoder
    g(x, W_in, b_in, nullptr, bufH, 256, 1);                       // h = swish(x@W_in+b)
    for (int i = 0; i < 3; ++i) {
        g(bufH, Wb1 + (size_t)i * 65536, bb1 + i * 256, nullptr, bufT, 256, 1);
        g(bufT, Wb2 + (size_t)i * 65536, bb2 + i * 256, bufH, bufH, 256, 0);  // residual, in-place ok
    }
    g(bufH, W_fo, b_fo, nullptr, bufT, 256, 0);                    // features -> bufT
    g(bufT, W_lat, b_lat, nullptr, bufH, 128, 0);                  // latent_params -> bufH
    mu_s_kernel<<<dim3(NB * 64 / 256), blk, 0, stream>>>(bufH, mu_o, s_o);
    g(bufT, W_init, b_init, nullptr, zpath, 64, 0);                // z0 -> z_path[0]

    // SDE: 63 steps, persistent
    sde_kernel<<<dim3(NB / SROWS), blk, 0, stream>>>(
        ts, noise, Wd1, bd1, Wd2, bd2, Wd3, bd3, Wg1, bg1, Wg2, bg2, zpath);
}